// Round 9
// baseline (470.927 us; speedup 1.0000x reference)
//
#include <hip/hip_runtime.h>

typedef short s8v __attribute__((ext_vector_type(8)));
typedef float f4v __attribute__((ext_vector_type(4)));

#define MFMA16(a,b,c) __builtin_amdgcn_mfma_f32_16x16x32_bf16(a,b,c,0,0,0)

#define TOK 36864
#define SEQ 9216
#define CH 128
#define WL 2304
#define ATTN_SCALE (1.0f/1179648.0f)

__device__ __forceinline__ float b2f(unsigned short u){
  union{unsigned i; float f;} c; c.i = ((unsigned)u)<<16; return c.f;
}
__device__ __forceinline__ unsigned short f2b(float f){
  union{float f; unsigned i;} c; c.f = f;
  unsigned r = c.i + 0x7fffu + ((c.i>>16)&1u);
  return (unsigned short)(r>>16);
}

// ---------------- K0: hi/lo weight transpose + f32 param pack ----------------
__global__ __launch_bounds__(256) void k_prep(const float* __restrict__ wgq,
    const float* __restrict__ wkv, const float* __restrict__ wo1, const float* __restrict__ wo2,
    const float* __restrict__ bgq, const float* __restrict__ bkv, const float* __restrict__ bo1,
    const float* __restrict__ lng, const float* __restrict__ lnb,
    unsigned short* __restrict__ Wth, unsigned short* __restrict__ Wtl,
    unsigned short* __restrict__ W1h, unsigned short* __restrict__ W1l,
    unsigned short* __restrict__ W2h, unsigned short* __restrict__ W2l,
    float* __restrict__ Pf)
{
  int idx = blockIdx.x*256 + threadIdx.x;
  if (idx < 65536){
    int n = idx>>7, k = idx&127;
    float v = (n<256) ? wgq[k*256+n] : wkv[k*256+(n-256)];
    unsigned short h = f2b(v);
    Wth[idx] = h; Wtl[idx] = f2b(v - b2f(h));
  } else if (idx < 81920){
    int t2 = idx-65536; int n = t2>>7, k = t2&127;
    float v = wo1[k*128+n];
    unsigned short h = f2b(v);
    W1h[t2] = h; W1l[t2] = f2b(v - b2f(h));
  } else if (idx < 98304){
    int t2 = idx-81920; int n = t2>>7, k = t2&127;
    float v = wo2[k*128+n];
    unsigned short h = f2b(v);
    W2h[t2] = h; W2l[t2] = f2b(v - b2f(h));
  } else if (idx < 99200){
    int j = idx-98304;
    float v;
    if (j<256)      v = bgq[j];
    else if (j<512) v = bkv[j-256];
    else if (j<640) v = bo1[j-512];
    else if (j<768) v = lng[j-640];
    else            v = lnb[j-768];
    Pf[j] = v;   // f32: [bgq|bkv|bo1|lng|lnb]
  }
}

// ---------------- K1: LN + projection (hi/lo MFMA) + silu + window scatter ----------------
__global__ __launch_bounds__(256) void k_proj(const float* __restrict__ src,
    const unsigned short* __restrict__ Wth, const unsigned short* __restrict__ Wtl,
    const float* __restrict__ Pf,
    float* __restrict__ gate, unsigned short* __restrict__ Qw,
    unsigned short* __restrict__ Kw, unsigned short* __restrict__ Vt)
{
  __shared__ __align__(16) short lSh[64][136];
  __shared__ __align__(16) short lSl[64][136];
  const int tid = threadIdx.x;
  const int w = tid>>6, l = tid&63, l16 = l&15, quad = l>>4;
  const int m0 = blockIdx.x*64;

  { // f32 LayerNorm of 64 rows; hi/lo bf16 split into LDS
    int row = tid>>2, lam = tid&3;
    const float* sp = src + (m0+row)*CH + lam*32;
    float v[32]; float s = 0.f, sq = 0.f;
#pragma unroll
    for (int j=0;j<32;j++){ v[j] = sp[j]; s += v[j]; sq += v[j]*v[j]; }
    s += __shfl_xor(s,1); sq += __shfl_xor(sq,1);
    s += __shfl_xor(s,2); sq += __shfl_xor(sq,2);
    float mean = s*(1.f/128.f);
    float rstd = rsqrtf(sq*(1.f/128.f) - mean*mean + 1e-5f);
#pragma unroll
    for (int j=0;j<32;j++){
      int c = lam*32 + j;
      float x = (v[j]-mean)*rstd*Pf[640+c] + Pf[768+c];
      unsigned short h = f2b(x);
      lSh[row][c] = (short)h;
      lSl[row][c] = (short)f2b(x - b2f(h));
    }
  }
  __syncthreads();

  s8v aH[4], aL[4];
#pragma unroll
  for (int kc=0;kc<4;kc++){
    aH[kc] = *(const s8v*)&lSh[w*16+l16][kc*32+quad*8];
    aL[kc] = *(const s8v*)&lSl[w*16+l16][kc*32+quad*8];
  }

  int tokv[4], gidx[4], posv[4];
#pragma unroll
  for (int r=0;r<4;r++){
    int token = m0 + w*16 + quad*4 + r;
    int bi = token / SEQ; int t = token - bi*SEQ;
    int i = t / 96; int j = t - i*96;
    int p = i - 24; if (p<0) p += 96;
    int q = j - 24; if (q<0) q += 96;
    int ihh = (p>=48); int rr = p - ihh*48;
    int iww = (q>=48); int ss = q - iww*48;
    tokv[r] = token;
    gidx[r] = bi*4 + ihh*2 + iww;
    posv[r] = rr*48 + ss;
  }

#pragma unroll
  for (int chunk=0; chunk<2; chunk++){
    f4v acc[16];
#pragma unroll
    for (int nt=0;nt<16;nt++){
      f4v z = {0.f,0.f,0.f,0.f}; acc[nt] = z;
      const unsigned short* bpH = Wth + (chunk*256 + nt*16 + l16)*CH + quad*8;
      const unsigned short* bpL = Wtl + (chunk*256 + nt*16 + l16)*CH + quad*8;
#pragma unroll
      for (int kc=0;kc<4;kc++){
        s8v bh = *(const s8v*)(bpH + kc*32);
        acc[nt] = MFMA16(aH[kc], bh, acc[nt]);
        acc[nt] = MFMA16(aL[kc], bh, acc[nt]);
        acc[nt] = MFMA16(aH[kc], *(const s8v*)(bpL + kc*32), acc[nt]);
      }
    }
#pragma unroll
    for (int nt=0;nt<16;nt++){
      int col = chunk*256 + nt*16 + l16;
      float bias = Pf[col];
#pragma unroll
      for (int r=0;r<4;r++){
        float z = acc[nt][r] + bias;
        z = z / (1.0f + __expf(-z));            // silu
        if (col < 128){
          gate[tokv[r]*CH + col] = z;           // f32, parked in d_out
        } else if (col < 256){
          Qw[(gidx[r]*WL + posv[r])*CH + (col-128)] = f2b(z);
        } else if (col < 384){
          Kw[(gidx[r]*WL + posv[r])*CH + (col-256)] = f2b(z);
        } else {
          Vt[gidx[r]*CH*WL + (col-384)*WL + posv[r]] = f2b(z);  // V^T: [win][ch][pos]
        }
      }
    }
  }
}

// ---------------- K2: windowed attention, BM=64, r6 3-barrier structure ----------------
// AH aliases Qw: each block reads exactly the Q rows it later writes (no __restrict__).
__global__ __launch_bounds__(256) void k_attn(const unsigned short* Qw,
    const unsigned short* __restrict__ Kw, const unsigned short* __restrict__ Vt,
    unsigned short* AH, unsigned short* __restrict__ AL)
{
  __shared__ __align__(16) short lK[64][136];   // K tile [key][ch]
  __shared__ __align__(16) short lV[128][72];   // V tile [ch][key]
  __shared__ __align__(16) short lP[4][16][72]; // per-wave P [row][key]
  const int tid = threadIdx.x;
  const int w = tid>>6, l = tid&63, l16 = l&15, quad = l>>4;
  const int g = blockIdx.y;
  const int q0 = blockIdx.x*64;
  const int ih = (g>>1)&1, iw = g&1;

  const unsigned short* qp = Qw + (g*WL + q0 + w*16 + l16)*CH + quad*8;
  s8v aQ[4];
#pragma unroll
  for (int kc=0;kc<4;kc++) aQ[kc] = *(const s8v*)(qp + kc*32);

  int qrl[4], qcl[4];
#pragma unroll
  for (int r=0;r<4;r++){
    int qpj = q0 + w*16 + quad*4 + r;
    int qr = qpj/48, qs = qpj - qr*48;
    qrl[r] = (qr>=24); qcl[r] = (qs>=24);
  }

  f4v O[8];
#pragma unroll
  for (int i=0;i<8;i++){ f4v z = {0.f,0.f,0.f,0.f}; O[i] = z; }
  float lsum[4] = {0.f,0.f,0.f,0.f};

  for (int k0=0; k0<WL; k0+=64){
    __syncthreads();
    {
      const unsigned short* Kg = Kw + (g*WL + k0)*CH;
#pragma unroll
      for (int it=0;it<4;it++){
        int li = tid + it*256;
        int row = li>>4, ch = (li&15)*8;
        *(s8v*)&lK[row][ch] = *(const s8v*)(Kg + row*CH + ch);
      }
      const unsigned short* Vg = Vt + g*CH*WL + k0;
#pragma unroll
      for (int it=0;it<4;it++){
        int idx = tid + it*256;
        int ch = idx>>3, pb = (idx&7)*8;
        *(s8v*)&lV[ch][pb] = *(const s8v*)(Vg + ch*WL + pb);
      }
    }
    __syncthreads();

    f4v S[4];
#pragma unroll
    for (int nt=0;nt<4;nt++){
      f4v z = {0.f,0.f,0.f,0.f}; S[nt] = z;
#pragma unroll
      for (int kc=0;kc<4;kc++)
        S[nt] = MFMA16(aQ[kc], *(const s8v*)&lK[nt*16+l16][kc*32+quad*8], S[nt]);
    }

#pragma unroll
    for (int nt=0;nt<4;nt++){
      int key = k0 + nt*16 + l16;
      int kr = key/48, ks = key - kr*48;
      int krl = (kr>=24), kcl = (ks>=24);
#pragma unroll
      for (int r=0;r<4;r++){
        bool masked = (ih && (krl != qrl[r])) || (iw && (kcl != qcl[r]));
        float p = masked ? 0.0f : __expf(S[nt][r]*ATTN_SCALE);
        unsigned short pb = f2b(p);
        lsum[r] += b2f(pb);
        lP[w][quad*4+r][nt*16+l16] = (short)pb;
      }
    }
    __syncthreads();

#pragma unroll
    for (int kc2=0;kc2<2;kc2++){
      s8v aP = *(const s8v*)&lP[w][l16][kc2*32+quad*8];
#pragma unroll
      for (int nt=0;nt<8;nt++)
        O[nt] = MFMA16(aP, *(const s8v*)&lV[nt*16+l16][kc2*32+quad*8], O[nt]);
    }
  }

#pragma unroll
  for (int r=0;r<4;r++){
#pragma unroll
    for (int m=1;m<16;m<<=1) lsum[r] += __shfl_xor(lsum[r], m);
  }
  unsigned short* outH = AH + (g*WL + q0 + w*16)*CH;
  unsigned short* outL = AL + (g*WL + q0 + w*16)*CH;
#pragma unroll
  for (int nt=0;nt<8;nt++){
#pragma unroll
    for (int r=0;r<4;r++){
      float o = O[nt][r] / lsum[r];
      unsigned short h = f2b(o);
      outH[(quad*4+r)*CH + nt*16 + l16] = h;
      outL[(quad*4+r)*CH + nt*16 + l16] = f2b(o - b2f(h));
    }
  }
}

// ---------------- K3: unwindow + gate + o1(silu) + o2 + residual, hi/lo path ----------------
__global__ __launch_bounds__(256) void k_out(const unsigned short* __restrict__ AH,
    const unsigned short* __restrict__ AL,
    const unsigned short* __restrict__ W1h, const unsigned short* __restrict__ W1l,
    const float* __restrict__ Pf,
    const unsigned short* __restrict__ W2h, const unsigned short* __restrict__ W2l,
    const float* __restrict__ src, float* out)
{
  __shared__ __align__(16) short lAh[64][136];
  __shared__ __align__(16) short lAl[64][136];
  __shared__ __align__(16) short lUh[4][16][136];
  __shared__ __align__(16) short lUl[4][16][136];
  const int tid = threadIdx.x;
  const int w = tid>>6, l = tid&63, l16 = l&15, quad = l>>4;
  const int m0 = blockIdx.x*64;
  {
    int r_loc = tid>>2;
    int cb = (tid&3)*32;
    int token = m0 + r_loc;
    int bi = token / SEQ; int t = token - bi*SEQ;
    int i = t / 96; int j = t - i*96;
    int p = i - 24; if (p<0) p += 96;
    int q = j - 24; if (q<0) q += 96;
    int ihh = (p>=48); int rr = p - ihh*48;
    int iww = (q>=48); int ss = q - iww*48;
    int wb = (bi*4 + ihh*2 + iww)*WL + rr*48 + ss;
    const unsigned short* avH = AH + wb*CH + cb;
    const unsigned short* avL = AL + wb*CH + cb;
    const float* gv = out + token*CH + cb;    // gate parked in out[0:TOK*CH)
#pragma unroll
    for (int u=0;u<4;u++){
      s8v h8 = *(const s8v*)(avH + u*8);
      s8v l8 = *(const s8v*)(avL + u*8);
      s8v oh, ol;
#pragma unroll
      for (int jj=0;jj<8;jj++){
        float a = b2f((unsigned short)h8[jj]) + b2f((unsigned short)l8[jj]);
        float pr = a * gv[u*8 + jj];
        unsigned short ph = f2b(pr);
        oh[jj] = (short)ph;
        ol[jj] = (short)f2b(pr - b2f(ph));
      }
      *(s8v*)&lAh[r_loc][cb + u*8] = oh;
      *(s8v*)&lAl[r_loc][cb + u*8] = ol;
    }
  }
  __syncthreads();

  s8v aH[4], aL[4];
#pragma unroll
  for (int kc=0;kc<4;kc++){
    aH[kc] = *(const s8v*)&lAh[w*16+l16][kc*32+quad*8];
    aL[kc] = *(const s8v*)&lAl[w*16+l16][kc*32+quad*8];
  }
  f4v acc[8];
#pragma unroll
  for (int nt=0;nt<8;nt++){
    f4v z = {0.f,0.f,0.f,0.f}; acc[nt] = z;
    const unsigned short* bpH = W1h + (nt*16+l16)*CH + quad*8;
    const unsigned short* bpL = W1l + (nt*16+l16)*CH + quad*8;
#pragma unroll
    for (int kc=0;kc<4;kc++){
      s8v bh = *(const s8v*)(bpH + kc*32);
      acc[nt] = MFMA16(aH[kc], bh, acc[nt]);
      acc[nt] = MFMA16(aL[kc], bh, acc[nt]);
      acc[nt] = MFMA16(aH[kc], *(const s8v*)(bpL + kc*32), acc[nt]);
    }
  }
#pragma unroll
  for (int nt=0;nt<8;nt++){
    int col = nt*16 + l16;
    float bias = Pf[512+col];   // bo1
#pragma unroll
    for (int r=0;r<4;r++){
      float z = acc[nt][r] + bias;
      z = z / (1.0f + __expf(-z));
      unsigned short h = f2b(z);
      lUh[w][quad*4+r][col] = (short)h;
      lUl[w][quad*4+r][col] = (short)f2b(z - b2f(h));
    }
  }
  __syncthreads();

  s8v uH[4], uL[4];
#pragma unroll
  for (int kc=0;kc<4;kc++){
    uH[kc] = *(const s8v*)&lUh[w][l16][kc*32+quad*8];
    uL[kc] = *(const s8v*)&lUl[w][l16][kc*32+quad*8];
  }
  f4v acc2[8];
#pragma unroll
  for (int nt=0;nt<8;nt++){
    f4v z = {0.f,0.f,0.f,0.f}; acc2[nt] = z;
    const unsigned short* bpH = W2h + (nt*16+l16)*CH + quad*8;
    const unsigned short* bpL = W2l + (nt*16+l16)*CH + quad*8;
#pragma unroll
    for (int kc=0;kc<4;kc++){
      s8v bh = *(const s8v*)(bpH + kc*32);
      acc2[nt] = MFMA16(uH[kc], bh, acc2[nt]);
      acc2[nt] = MFMA16(uL[kc], bh, acc2[nt]);
      acc2[nt] = MFMA16(uH[kc], *(const s8v*)(bpL + kc*32), acc2[nt]);
    }
  }
#pragma unroll
  for (int nt=0;nt<8;nt++){
#pragma unroll
    for (int r=0;r<4;r++){
      int token = m0 + w*16 + quad*4 + r;
      int col = nt*16 + l16;
      float y = acc2[nt][r] + src[token*CH + col];
      out[token*CH + col] = y;
      out[TOK*CH + token*CH + col] = y;
    }
  }
}

extern "C" void kernel_launch(void* const* d_in, const int* in_sizes, int n_in,
                              void* d_out, int out_size, void* d_ws, size_t ws_size,
                              hipStream_t stream)
{
  const float* src = (const float*)d_in[0];
  const float* lng = (const float*)d_in[5];
  const float* lnb = (const float*)d_in[6];
  const float* wgq = (const float*)d_in[7];
  const float* bgq = (const float*)d_in[8];
  const float* wkv = (const float*)d_in[9];
  const float* bkv = (const float*)d_in[10];
  const float* wo1 = (const float*)d_in[11];
  const float* bo1 = (const float*)d_in[12];
  const float* wo2 = (const float*)d_in[13];

  // Workspace 36.4 MiB: Pf | Wth | Wtl | W1h | W1l | W2h | W2l | Qw(AH) | Kw | Vt | AL
  char* ws = (char*)d_ws;
  float*          Pf  = (float*)(ws);                      // 896 f32
  unsigned short* Wth = (unsigned short*)(ws + 4096);
  unsigned short* Wtl = (unsigned short*)(ws + 135168);
  unsigned short* W1h = (unsigned short*)(ws + 266240);
  unsigned short* W1l = (unsigned short*)(ws + 299008);
  unsigned short* W2h = (unsigned short*)(ws + 331776);
  unsigned short* W2l = (unsigned short*)(ws + 364544);
  unsigned short* Qw  = (unsigned short*)(ws + 397312);    // AH aliases after k_attn
  unsigned short* Kw  = (unsigned short*)(ws + 9834496);
  unsigned short* Vt  = (unsigned short*)(ws + 19271680);  // [g][ch][pos]
  unsigned short* AL  = (unsigned short*)(ws + 28708864);
  float* out = (float*)d_out;                              // gate in out[0:TOK*CH)

  k_prep<<<dim3(388),   dim3(256), 0, stream>>>(wgq, wkv, wo1, wo2, bgq, bkv, bo1, lng, lnb,
                                                Wth, Wtl, W1h, W1l, W2h, W2l, Pf);
  k_proj<<<dim3(576),   dim3(256), 0, stream>>>(src, Wth, Wtl, Pf, out, Qw, Kw, Vt);
  k_attn<<<dim3(36,16), dim3(256), 0, stream>>>(Qw, Kw, Vt, Qw, AL);
  k_out <<<dim3(576),   dim3(256), 0, stream>>>(Qw, AL, W1h, W1l, Pf, W2h, W2l, src, out);
}